// Round 1
// baseline (36163.559 us; speedup 1.0000x reference)
//
#include <hip/hip_runtime.h>
#include <hip/hip_bf16.h>

#define T_STEPS 512
#define BATCH   64
#define HID     1024
#define NWG     64

typedef __attribute__((ext_vector_type(8))) short short8;
typedef __attribute__((ext_vector_type(4))) float f32x4;

static __device__ __forceinline__ float b2f(unsigned short u){
  union { unsigned u; float f; } c; c.u = ((unsigned)u) << 16; return c.f;
}
static __device__ __forceinline__ unsigned short f2b(float f){
  union { float f; unsigned u; } c; c.f = f;
  unsigned r = c.u + 0x7fffu + ((c.u >> 16) & 1u);
  return (unsigned short)(r >> 16);
}
static __device__ __forceinline__ float sigm(float x){ return 1.0f / (1.0f + __expf(-x)); }
static __device__ __forceinline__ float tanh_fast(float x){ return 2.0f / (1.0f + __expf(-2.0f * x)) - 1.0f; }

// ---------------- init: zero barrier flags + bf16 H state ----------------
__global__ void gru_init_k(int* __restrict__ flags, unsigned* __restrict__ hbf){
  if (blockIdx.x == 0)
    for (int j = threadIdx.x; j < NWG * 16; j += 256) flags[j] = 0;
  for (int j = threadIdx.x + blockIdx.x * 256; j < BATCH * HID / 2; j += 256 * gridDim.x)
    hbf[j] = 0u;
}

// ---------------- cast inputs fp32 -> bf16 ----------------
__global__ void gru_castx_k(const float4* __restrict__ in, unsigned short* __restrict__ out, int n4){
  int stride = gridDim.x * blockDim.x;
  for (int i = blockIdx.x * blockDim.x + threadIdx.x; i < n4; i += stride){
    float4 v = in[i];
    ushort4 o;
    o.x = f2b(v.x); o.y = f2b(v.y); o.z = f2b(v.z); o.w = f2b(v.w);
    *(ushort4*)(out + (size_t)i * 4) = o;
  }
}

// ---------------- transpose + cast weights: Wt[g][n][k] = W_g[k][n] ----------------
__global__ void gru_prepw_k(const float* __restrict__ w0, const float* __restrict__ w1,
                            const float* __restrict__ w2, const float* __restrict__ w3,
                            const float* __restrict__ w4, const float* __restrict__ w5,
                            unsigned short* __restrict__ wt){
  __shared__ float tile[32][33];
  const float* src;
  switch (blockIdx.z){
    case 0: src = w0; break; case 1: src = w1; break; case 2: src = w2; break;
    case 3: src = w3; break; case 4: src = w4; break; default: src = w5; break;
  }
  int tx = threadIdx.x, ty = threadIdx.y;
  int x0 = blockIdx.x * 32, y0 = blockIdx.y * 32;
  #pragma unroll
  for (int i = 0; i < 32; i += 8)
    tile[ty + i][tx] = src[(size_t)(y0 + ty + i) * HID + x0 + tx];
  __syncthreads();
  unsigned short* dst = wt + (size_t)blockIdx.z * HID * HID;
  #pragma unroll
  for (int i = 0; i < 32; i += 8)
    dst[(size_t)(x0 + ty + i) * HID + y0 + tx] = f2b(tile[tx][ty + i]);
}

// ---------------- persistent GRU scan ----------------
static __device__ __forceinline__ void wait_ge(const int* flags, int target, int lane){
  for (;;){
    int v = __hip_atomic_load(flags + lane * 16, __ATOMIC_RELAXED, __HIP_MEMORY_SCOPE_AGENT);
    if (__all(v >= target)) return;
    __builtin_amdgcn_s_sleep(2);
  }
}

__global__ __launch_bounds__(512, 2) void gru_scan_k(
    const unsigned short* __restrict__ xbf,   // [T][64][1024] bf16
    const unsigned short* __restrict__ wt,    // [6][1024][1024] bf16, [n][k]
    const float* __restrict__ bz, const float* __restrict__ br, const float* __restrict__ bh,
    float* __restrict__ out,                  // [T][64][1024] fp32 + [64][1024] H_final
    unsigned short* __restrict__ hbf,         // [64][1024] bf16 H state
    unsigned short* __restrict__ rhbf,        // [64][1024] bf16 R*H
    int* __restrict__ flags)
{
  const int wg   = blockIdx.x;        // owns cols [wg*16, wg*16+16)
  const int wave = threadIdx.x >> 6;  // 0..7
  const int lane = threadIdx.x & 63;
  const int l16  = lane & 15;
  const int kq   = lane >> 4;         // 0..3
  const int rb   = wave & 3;          // row block (16 rows each)
  const bool zp  = (wave < 4);        // waves 0-3: Z path + phase B; 4-7: R path
  const int col  = wg * 16 + l16;
  const int arow = rb * 16 + l16;             // A-fragment row
  const int crow0 = rb * 16 + kq * 4;         // C-fragment row base (acc[j] -> crow0+j)

  const unsigned short* wxp  = wt + (size_t)(zp ? 0 : 2) * HID * HID + (size_t)col * HID + kq * 8;
  const unsigned short* whp  = wt + (size_t)(zp ? 1 : 3) * HID * HID + (size_t)col * HID + kq * 8;
  const unsigned short* wxhp = wt + (size_t)4 * HID * HID + (size_t)col * HID + kq * 8;
  const unsigned short* whhp = wt + (size_t)5 * HID * HID + (size_t)col * HID + kq * 8;
  const unsigned short* hrow  = hbf  + (size_t)arow * HID + kq * 8;
  const unsigned short* rhrow = rhbf + (size_t)arow * HID + kq * 8;
  const float bg  = (zp ? bz : br)[col];
  const float bhv = bh[col];

  for (int t = 0; t < T_STEPS; ++t){
    const unsigned short* xrow = xbf + ((size_t)t * BATCH + arow) * HID + kq * 8;

    // ---- phase A: x-part first (independent of barrier) ----
    f32x4 acc = {0.f, 0.f, 0.f, 0.f};
    #pragma unroll 4
    for (int kk = 0; kk < HID; kk += 32)
      acc = __builtin_amdgcn_mfma_f32_16x16x32_bf16(
          *(const short8*)(xrow + kk), *(const short8*)(wxp + kk), acc, 0, 0, 0);

    wait_ge(flags, 2 * t, lane);   // H_{t-1} published by all WGs
    __threadfence();

    #pragma unroll 4
    for (int kk = 0; kk < HID; kk += 32)
      acc = __builtin_amdgcn_mfma_f32_16x16x32_bf16(
          *(const short8*)(hrow + kk), *(const short8*)(whp + kk), acc, 0, 0, 0);

    float g[4], hp[4];
    #pragma unroll
    for (int j = 0; j < 4; ++j){
      hp[j] = b2f(hbf[(size_t)(crow0 + j) * HID + col]);
      g[j]  = sigm(acc[j] + bg);
    }
    if (!zp){
      #pragma unroll
      for (int j = 0; j < 4; ++j)
        rhbf[(size_t)(crow0 + j) * HID + col] = f2b(g[j] * hp[j]);
    }
    __threadfence();
    __syncthreads();
    if (threadIdx.x == 0)
      __hip_atomic_store(flags + wg * 16, 2 * t + 1, __ATOMIC_RELEASE, __HIP_MEMORY_SCOPE_AGENT);

    // ---- phase B (waves 0-3): H_tilde, combine, publish H_t ----
    if (zp){
      f32x4 a2 = {0.f, 0.f, 0.f, 0.f};
      #pragma unroll 4
      for (int kk = 0; kk < HID; kk += 32)      // xh part: no barrier needed, hides poll
        a2 = __builtin_amdgcn_mfma_f32_16x16x32_bf16(
            *(const short8*)(xrow + kk), *(const short8*)(wxhp + kk), a2, 0, 0, 0);
      wait_ge(flags, 2 * t + 1, lane);          // R*H published by all WGs
      __threadfence();
      #pragma unroll 4
      for (int kk = 0; kk < HID; kk += 32)
        a2 = __builtin_amdgcn_mfma_f32_16x16x32_bf16(
            *(const short8*)(rhrow + kk), *(const short8*)(whhp + kk), a2, 0, 0, 0);
      #pragma unroll
      for (int j = 0; j < 4; ++j){
        float ht = tanh_fast(a2[j] + bhv);
        float hn = g[j] * hp[j] + (1.0f - g[j]) * ht;
        out[((size_t)t * BATCH + crow0 + j) * HID + col] = hn;
        hbf[(size_t)(crow0 + j) * HID + col] = f2b(hn);
        if (t == T_STEPS - 1)
          out[(size_t)T_STEPS * BATCH * HID + (size_t)(crow0 + j) * HID + col] = hn;
      }
    }
    __threadfence();
    __syncthreads();
    if (threadIdx.x == 0)
      __hip_atomic_store(flags + wg * 16, 2 * t + 2, __ATOMIC_RELEASE, __HIP_MEMORY_SCOPE_AGENT);
  }
}

extern "C" void kernel_launch(void* const* d_in, const int* in_sizes, int n_in,
                              void* d_out, int out_size, void* d_ws, size_t ws_size,
                              hipStream_t stream){
  const float* inputs = (const float*)d_in[0];
  const float* W_xz = (const float*)d_in[1];
  const float* W_hz = (const float*)d_in[2];
  const float* b_z  = (const float*)d_in[3];
  const float* W_xr = (const float*)d_in[4];
  const float* W_hr = (const float*)d_in[5];
  const float* b_r  = (const float*)d_in[6];
  const float* W_xh = (const float*)d_in[7];
  const float* W_hh = (const float*)d_in[8];
  const float* b_h  = (const float*)d_in[9];
  float* out = (float*)d_out;

  char* ws = (char*)d_ws;
  int*            flags = (int*)ws;                                  // 4 KiB
  unsigned short* hbf   = (unsigned short*)(ws + 4096);              // 128 KiB
  unsigned short* rhbf  = (unsigned short*)(ws + 4096 + 131072);     // 128 KiB
  unsigned short* wt    = (unsigned short*)(ws + 266240);            // 12 MiB
  unsigned short* xbf   = (unsigned short*)(ws + 266240 + 12582912); // 64 MiB
  // total ws needed: ~76.3 MB

  gru_init_k<<<8, 256, 0, stream>>>(flags, (unsigned*)hbf);
  gru_castx_k<<<2048, 256, 0, stream>>>((const float4*)inputs, xbf, T_STEPS * BATCH * HID / 4);
  gru_prepw_k<<<dim3(32, 32, 6), dim3(32, 8), 0, stream>>>(W_xz, W_hz, W_xr, W_hr, W_xh, W_hh, wt);
  gru_scan_k<<<NWG, 512, 0, stream>>>(xbf, wt, b_z, b_r, b_h, out, hbf, rhbf, flags);
}

// Round 2
// 18999.490 us; speedup vs baseline: 1.9034x; 1.9034x over previous
//
#include <hip/hip_runtime.h>
#include <hip/hip_bf16.h>

#define T_STEPS 512
#define BATCH   64
#define HID     1024
#define NWG     64

typedef __attribute__((ext_vector_type(8))) short short8;
typedef __attribute__((ext_vector_type(4))) float f32x4;

static __device__ __forceinline__ float b2f(unsigned short u){
  union { unsigned u; float f; } c; c.u = ((unsigned)u) << 16; return c.f;
}
static __device__ __forceinline__ unsigned short f2b(float f){
  union { float f; unsigned u; } c; c.f = f;
  unsigned r = c.u + 0x7fffu + ((c.u >> 16) & 1u);
  return (unsigned short)(r >> 16);
}
static __device__ __forceinline__ float sigm(float x){ return 1.0f / (1.0f + __expf(-x)); }
static __device__ __forceinline__ float tanh_fast(float x){ return 2.0f / (1.0f + __expf(-2.0f * x)) - 1.0f; }

// ---------------- init: zero barrier flags + bf16 H state ----------------
__global__ void gru_init_k(int* __restrict__ flags, unsigned* __restrict__ hbf){
  if (blockIdx.x == 0)
    for (int j = threadIdx.x; j < NWG * 16; j += 256) flags[j] = 0;
  for (int j = threadIdx.x + blockIdx.x * 256; j < BATCH * HID / 2; j += 256 * gridDim.x)
    hbf[j] = 0u;
}

// ---------------- cast inputs fp32 -> bf16 ----------------
__global__ void gru_castx_k(const float4* __restrict__ in, unsigned short* __restrict__ out, int n4){
  int stride = gridDim.x * blockDim.x;
  for (int i = blockIdx.x * blockDim.x + threadIdx.x; i < n4; i += stride){
    float4 v = in[i];
    ushort4 o;
    o.x = f2b(v.x); o.y = f2b(v.y); o.z = f2b(v.z); o.w = f2b(v.w);
    *(ushort4*)(out + (size_t)i * 4) = o;
  }
}

// ---------------- transpose + cast weights: Wt[g][n][k] = W_g[k][n] ----------------
__global__ void gru_prepw_k(const float* __restrict__ w0, const float* __restrict__ w1,
                            const float* __restrict__ w2, const float* __restrict__ w3,
                            const float* __restrict__ w4, const float* __restrict__ w5,
                            unsigned short* __restrict__ wt){
  __shared__ float tile[32][33];
  const float* src;
  switch (blockIdx.z){
    case 0: src = w0; break; case 1: src = w1; break; case 2: src = w2; break;
    case 3: src = w3; break; case 4: src = w4; break; default: src = w5; break;
  }
  int tx = threadIdx.x, ty = threadIdx.y;
  int x0 = blockIdx.x * 32, y0 = blockIdx.y * 32;
  #pragma unroll
  for (int i = 0; i < 32; i += 8)
    tile[ty + i][tx] = src[(size_t)(y0 + ty + i) * HID + x0 + tx];
  __syncthreads();
  unsigned short* dst = wt + (size_t)blockIdx.z * HID * HID;
  #pragma unroll
  for (int i = 0; i < 32; i += 8)
    dst[(size_t)(x0 + ty + i) * HID + y0 + tx] = f2b(tile[tx][ty + i]);
}

// ---------------- wave-0-only grid sync ----------------
static __device__ __forceinline__ void waitflags(const int* flags, int target, int lane){
  for (;;){
    int v = __hip_atomic_load(flags + lane * 16, __ATOMIC_RELAXED, __HIP_MEMORY_SCOPE_AGENT);
    if (__all(v >= target)) break;
  }
  __builtin_amdgcn_fence(__ATOMIC_ACQUIRE, "agent");  // invalidate L1/L2 once per WG
}

// ---------------- persistent GRU scan ----------------
__global__ __launch_bounds__(512, 1) void gru_scan_k(
    const unsigned short* __restrict__ xbf,   // [T][64][1024] bf16
    const unsigned short* __restrict__ wt,    // [6][1024][1024] bf16, [n][k]
    const float* __restrict__ bz, const float* __restrict__ br, const float* __restrict__ bh,
    float* __restrict__ out,                  // [T][64][1024] fp32 + [64][1024] H_final
    unsigned short* __restrict__ hbf,         // [64][1024] bf16 H state
    unsigned short* __restrict__ rhbf,        // [64][1024] bf16 R*H
    int* __restrict__ flags)
{
  // 3 recurrent weight matrices staged in LDS: [mat][col16][1024 k], padded to 1032
  __shared__ unsigned short wl[3 * 16 * 1032];   // 99072 B
  __shared__ float hlds[BATCH * 16];             // this WG's H tile fp32, [row][l16]

  const int wg   = blockIdx.x;
  const int tid  = threadIdx.x;
  const int wave = tid >> 6;
  const int lane = tid & 63;
  const int l16  = lane & 15;
  const int kq   = lane >> 4;
  const int rb   = wave & 3;
  const bool zp  = (wave < 4);       // waves 0-3: Z path + phase B; 4-7: R path
  const int col  = wg * 16 + l16;
  const int arow = rb * 16 + l16;
  const int crow0 = rb * 16 + kq * 4;

  // stage Whz(1), Whr(3), Whh(5) -> LDS slots 0,1,2
  for (int idx = tid; idx < 3 * 16 * 128; idx += 512){
    int mat = idx / (16 * 128), rem = idx % (16 * 128), c = rem >> 7, kc = rem & 127;
    *(short8*)&wl[(size_t)(mat * 16 + c) * 1032 + kc * 8] =
      *(const short8*)&wt[(size_t)(2 * mat + 1) * HID * HID + (size_t)(wg * 16 + c) * HID + kc * 8];
  }
  for (int idx = tid; idx < BATCH * 16; idx += 512) hlds[idx] = 0.0f;

  const int woff_g = ((zp ? 0 : 1) * 16 + l16) * 1032 + kq * 8;
  const int woff_h = (2 * 16 + l16) * 1032 + kq * 8;

  const unsigned short* wxg  = wt + (size_t)(zp ? 0 : 2) * HID * HID + (size_t)col * HID + kq * 8;
  const unsigned short* wxh  = wt + (size_t)4 * HID * HID + (size_t)col * HID + kq * 8;
  const unsigned short* hrow  = hbf  + (size_t)arow * HID + kq * 8;
  const unsigned short* rhrow = rhbf + (size_t)arow * HID + kq * 8;
  const float bg  = (zp ? bz : br)[col];
  const float bhv = bh[col];

  float h[4] = {0.f, 0.f, 0.f, 0.f};   // persistent fp32 H for zp waves

  __syncthreads();

  for (int t = 0; t < T_STEPS; ++t){
    const unsigned short* xrow = xbf + ((size_t)t * BATCH + arow) * HID + kq * 8;

    // ---- phase A: x-part first (independent of barrier, hides wait) ----
    f32x4 acc = {0.f, 0.f, 0.f, 0.f};
    #pragma unroll 8
    for (int kk = 0; kk < HID; kk += 32)
      acc = __builtin_amdgcn_mfma_f32_16x16x32_bf16(
          *(const short8*)(xrow + kk), *(const short8*)(wxg + kk), acc, 0, 0, 0);

    if (wave == 0 && t > 0) waitflags(flags, 2 * t, lane);   // H_{t-1} published
    __syncthreads();

    #pragma unroll 8
    for (int kk = 0; kk < HID; kk += 32)
      acc = __builtin_amdgcn_mfma_f32_16x16x32_bf16(
          *(const short8*)(hrow + kk), *(const short8*)&wl[woff_g + kk], acc, 0, 0, 0);

    float gate[4];
    if (zp){
      #pragma unroll
      for (int j = 0; j < 4; ++j) gate[j] = sigm(acc[j] + bg);      // Z
    } else {
      #pragma unroll
      for (int j = 0; j < 4; ++j){
        float hp = hlds[(crow0 + j) * 16 + l16];
        float r  = sigm(acc[j] + bg);                               // R
        __builtin_nontemporal_store(f2b(r * hp), &rhbf[(size_t)(crow0 + j) * HID + col]);
      }
    }
    __syncthreads();   // drains each wave's stores (vmcnt) before release
    if (tid == 0)
      __hip_atomic_store(&flags[wg * 16], 2 * t + 1, __ATOMIC_RELEASE, __HIP_MEMORY_SCOPE_AGENT);

    // ---- phase B: H_tilde on waves 0-3; xh part before the wait ----
    f32x4 a2 = {0.f, 0.f, 0.f, 0.f};
    if (zp){
      #pragma unroll 8
      for (int kk = 0; kk < HID; kk += 32)
        a2 = __builtin_amdgcn_mfma_f32_16x16x32_bf16(
            *(const short8*)(xrow + kk), *(const short8*)(wxh + kk), a2, 0, 0, 0);
    }
    if (wave == 0) waitflags(flags, 2 * t + 1, lane);        // R*H published
    __syncthreads();
    if (zp){
      #pragma unroll 8
      for (int kk = 0; kk < HID; kk += 32)
        a2 = __builtin_amdgcn_mfma_f32_16x16x32_bf16(
            *(const short8*)(rhrow + kk), *(const short8*)&wl[woff_h + kk], a2, 0, 0, 0);
      #pragma unroll
      for (int j = 0; j < 4; ++j){
        float ht = tanh_fast(a2[j] + bhv);
        float hn = gate[j] * h[j] + (1.0f - gate[j]) * ht;
        h[j] = hn;
        hlds[(crow0 + j) * 16 + l16] = hn;
        __builtin_nontemporal_store(hn, &out[((size_t)t * BATCH + crow0 + j) * HID + col]);
        __builtin_nontemporal_store(f2b(hn), &hbf[(size_t)(crow0 + j) * HID + col]);
        if (t == T_STEPS - 1)
          __builtin_nontemporal_store(hn,
              &out[(size_t)T_STEPS * BATCH * HID + (size_t)(crow0 + j) * HID + col]);
      }
    }
    __syncthreads();
    if (tid == 0)
      __hip_atomic_store(&flags[wg * 16], 2 * t + 2, __ATOMIC_RELEASE, __HIP_MEMORY_SCOPE_AGENT);
  }
}

extern "C" void kernel_launch(void* const* d_in, const int* in_sizes, int n_in,
                              void* d_out, int out_size, void* d_ws, size_t ws_size,
                              hipStream_t stream){
  const float* inputs = (const float*)d_in[0];
  const float* W_xz = (const float*)d_in[1];
  const float* W_hz = (const float*)d_in[2];
  const float* b_z  = (const float*)d_in[3];
  const float* W_xr = (const float*)d_in[4];
  const float* W_hr = (const float*)d_in[5];
  const float* b_r  = (const float*)d_in[6];
  const float* W_xh = (const float*)d_in[7];
  const float* W_hh = (const float*)d_in[8];
  const float* b_h  = (const float*)d_in[9];
  float* out = (float*)d_out;

  char* ws = (char*)d_ws;
  int*            flags = (int*)ws;                                  // 4 KiB
  unsigned short* hbf   = (unsigned short*)(ws + 4096);              // 128 KiB
  unsigned short* rhbf  = (unsigned short*)(ws + 4096 + 131072);     // 128 KiB
  unsigned short* wt    = (unsigned short*)(ws + 266240);            // 12 MiB
  unsigned short* xbf   = (unsigned short*)(ws + 266240 + 12582912); // 64 MiB
  // total ws needed: ~76.3 MB (same as round 1)

  gru_init_k<<<8, 256, 0, stream>>>(flags, (unsigned*)hbf);
  gru_castx_k<<<2048, 256, 0, stream>>>((const float4*)inputs, xbf, T_STEPS * BATCH * HID / 4);
  gru_prepw_k<<<dim3(32, 32, 6), dim3(32, 8), 0, stream>>>(W_xz, W_hz, W_xr, W_hr, W_xh, W_hh, wt);
  gru_scan_k<<<NWG, 512, 0, stream>>>(xbf, wt, b_z, b_r, b_h, out, hbf, rhbf, flags);
}